// Round 1
// baseline (263.097 us; speedup 1.0000x reference)
//
#include <hip/hip_runtime.h>

#define BATCH 4
#define NPTS 8192
#define DIM 128
#define TOTAL_ROWS (BATCH * NPTS)   // 32768

typedef __attribute__((ext_vector_type(8))) short bf16x8;
typedef __attribute__((ext_vector_type(4))) float f32x4;

// fp32 -> bf16 round-to-nearest-even (bit trick; inputs are finite)
__device__ __forceinline__ unsigned short f2bf(float x) {
  unsigned u = __float_as_uint(x);
  u += 0x7FFFu + ((u >> 16) & 1u);
  return (unsigned short)(u >> 16);
}
// monotonic encoding of float for unsigned atomicMin (handles negatives)
__device__ __forceinline__ unsigned encf(float f) {
  unsigned b = __float_as_uint(f);
  return (b & 0x80000000u) ? ~b : (b | 0x80000000u);
}
__device__ __forceinline__ float decf(unsigned u) {
  unsigned b = (u & 0x80000000u) ? (u ^ 0x80000000u) : ~u;
  return __uint_as_float(b);
}

// ---- convert fp32 -> bf16, 8 elements per thread ----
__global__ void convert_bf16_kernel(const float* __restrict__ in,
                                    unsigned short* __restrict__ out) {
  int idx = blockIdx.x * blockDim.x + threadIdx.x;   // one per 8 elements
  const float4* ip = (const float4*)in + (size_t)idx * 2;
  float4 a = ip[0], b = ip[1];
  union { unsigned short us[8]; uint4 u4; } p;
  p.us[0] = f2bf(a.x); p.us[1] = f2bf(a.y); p.us[2] = f2bf(a.z); p.us[3] = f2bf(a.w);
  p.us[4] = f2bf(b.x); p.us[5] = f2bf(b.y); p.us[6] = f2bf(b.z); p.us[7] = f2bf(b.w);
  ((uint4*)out)[idx] = p.u4;
}

// ---- squared row norms: 64 rows/block, 4 threads/row ----
__global__ void norms_kernel(const float* __restrict__ x, float* __restrict__ n2) {
  int tid  = threadIdx.x;
  int row  = blockIdx.x * 64 + (tid >> 2);
  int part = tid & 3;
  const float4* xp = (const float4*)(x + (size_t)row * DIM) + part * 8;
  float s = 0.f;
  #pragma unroll
  for (int j = 0; j < 8; ++j) {
    float4 v = xp[j];
    s = fmaf(v.x, v.x, s); s = fmaf(v.y, v.y, s);
    s = fmaf(v.z, v.z, s); s = fmaf(v.w, v.w, s);
  }
  s += __shfl_xor(s, 1);
  s += __shfl_xor(s, 2);
  if (part == 0) n2[row] = s;
}

// ---- main: per wave, 64 f-rows (A in regs) x 2048-col m-slice ----
__global__ __launch_bounds__(256, 2)
void chamfer_mfma_kernel(const float* __restrict__ f,
                         const unsigned short* __restrict__ gbf,
                         const float* __restrict__ fn2,
                         const float* __restrict__ gn2,
                         unsigned int* __restrict__ rowmin,
                         unsigned int* __restrict__ colmin) {
  const int lane = threadIdx.x & 63;
  const int l15  = lane & 15;
  const int q    = lane >> 4;                       // 0..3
  const int wid  = blockIdx.x * 4 + (threadIdx.x >> 6);
  const int b     = wid >> 9;                       // 512 waves per batch
  const int rest  = wid & 511;
  const int slice = rest >> 7;                      // 0..3  (block's 4 waves share slice)
  const int rgrp  = rest & 127;                     // 0..127
  const int r0    = rgrp * 64;
  const int mbase = slice * 2048;
  const int bN    = b * NPTS;

  // A fragments: 4 tiles x 4 k-chunks, each 8 bf16 per lane.
  // A-frag layout: row = lane&15, k-chunk = lane>>4, 8 contiguous k per lane.
  bf16x8 af[4][4];
  const float* fb = f + (size_t)bN * DIM;
  #pragma unroll
  for (int t = 0; t < 4; ++t) {
    const float* frow = fb + (size_t)(r0 + t * 16 + l15) * DIM + q * 8;
    #pragma unroll
    for (int kc = 0; kc < 4; ++kc) {
      float4 x = *(const float4*)(frow + kc * 32);
      float4 y = *(const float4*)(frow + kc * 32 + 4);
      bf16x8 v;
      v[0] = (short)f2bf(x.x); v[1] = (short)f2bf(x.y);
      v[2] = (short)f2bf(x.z); v[3] = (short)f2bf(x.w);
      v[4] = (short)f2bf(y.x); v[5] = (short)f2bf(y.y);
      v[6] = (short)f2bf(y.z); v[7] = (short)f2bf(y.w);
      af[t][kc] = v;
    }
  }

  // fn2 for this lane's C rows: row = r0 + t*16 + q*4 + i  (m89 C/D layout)
  float fn2r[4][4];
  #pragma unroll
  for (int t = 0; t < 4; ++t)
    #pragma unroll
    for (int i = 0; i < 4; ++i)
      fn2r[t][i] = fn2[bN + r0 + t * 16 + q * 4 + i];

  float rmin[4][4];
  #pragma unroll
  for (int t = 0; t < 4; ++t)
    #pragma unroll
    for (int i = 0; i < 4; ++i) rmin[t][i] = 3.4e38f;

  const unsigned short* gb = gbf + (size_t)bN * DIM;

  for (int mt = 0; mt < 128; ++mt) {
    const int m0 = mbase + mt * 16;
    // B fragments: col = lane&15, same k-layout as A (symmetric load from row-major g)
    const unsigned short* grow = gb + (size_t)(m0 + l15) * DIM + q * 8;
    bf16x8 bf[4];
    #pragma unroll
    for (int kc = 0; kc < 4; ++kc) bf[kc] = *(const bf16x8*)(grow + kc * 32);
    float gn2v = gn2[bN + m0 + l15];

    f32x4 acc[4];
    #pragma unroll
    for (int t = 0; t < 4; ++t) {
      f32x4 a = {0.f, 0.f, 0.f, 0.f};
      #pragma unroll
      for (int kc = 0; kc < 4; ++kc)
        a = __builtin_amdgcn_mfma_f32_16x16x32_bf16(af[t][kc], bf[kc], a, 0, 0, 0);
      acc[t] = a;
    }

    // dis = fn2[row] + gn2[col] - 2*dot
    // rowmin tracks min_m (gn2 - 2dot)   (fn2 added at the end)
    // colmin: min over rows of (fn2 - 2dot), then + gn2
    float cmin = 3.4e38f;
    #pragma unroll
    for (int t = 0; t < 4; ++t)
      #pragma unroll
      for (int i = 0; i < 4; ++i) {
        float d = acc[t][i];
        rmin[t][i] = fminf(rmin[t][i], fmaf(-2.f, d, gn2v));
        cmin       = fminf(cmin,       fmaf(-2.f, d, fn2r[t][i]));
      }
    cmin = fminf(cmin, __shfl_xor(cmin, 16));
    cmin = fminf(cmin, __shfl_xor(cmin, 32));
    cmin += gn2v;                         // gn2v depends only on lane&15 -> consistent
    if (lane < 16) atomicMin(&colmin[bN + m0 + lane], encf(cmin));
  }

  // finalize row mins: reduce over the 16 column-lanes, add fn2, combine slices
  #pragma unroll
  for (int t = 0; t < 4; ++t)
    #pragma unroll
    for (int i = 0; i < 4; ++i) {
      float v = rmin[t][i];
      v = fminf(v, __shfl_xor(v, 1));
      v = fminf(v, __shfl_xor(v, 2));
      v = fminf(v, __shfl_xor(v, 4));
      v = fminf(v, __shfl_xor(v, 8));
      v += fn2r[t][i];
      if (l15 == 0)
        atomicMin(&rowmin[bN + r0 + t * 16 + q * 4 + i], encf(v));
    }
}

// ---- final scalar: mean of rowmins + mean of colmins ----
__global__ void reduce_kernel(const unsigned int* __restrict__ rowmin,
                              const unsigned int* __restrict__ colmin,
                              float* __restrict__ out) {
  __shared__ float sbuf[4];
  float s = 0.f;
  for (int i = threadIdx.x; i < TOTAL_ROWS; i += 256)
    s += decf(rowmin[i]) + decf(colmin[i]);
  #pragma unroll
  for (int o = 32; o >= 1; o >>= 1) s += __shfl_xor(s, o);
  if ((threadIdx.x & 63) == 0) sbuf[threadIdx.x >> 6] = s;
  __syncthreads();
  if (threadIdx.x == 0)
    out[0] = (sbuf[0] + sbuf[1] + sbuf[2] + sbuf[3]) / (float)TOTAL_ROWS;
}

extern "C" void kernel_launch(void* const* d_in, const int* in_sizes, int n_in,
                              void* d_out, int out_size, void* d_ws, size_t ws_size,
                              hipStream_t stream) {
  (void)in_sizes; (void)n_in; (void)out_size; (void)ws_size;
  const float* f  = (const float*)d_in[0];
  const float* f_ = (const float*)d_in[1];

  char* ws = (char*)d_ws;
  unsigned short* gbf = (unsigned short*)ws;                       // 8 MiB bf16 copy of f_
  float* fn2 = (float*)(ws + 8u * 1024u * 1024u);                  // 128 KiB
  float* gn2 = fn2 + TOTAL_ROWS;                                   // 128 KiB
  unsigned int* rowmin = (unsigned int*)(gn2 + TOTAL_ROWS);        // 128 KiB
  unsigned int* colmin = rowmin + TOTAL_ROWS;                      // 128 KiB

  convert_bf16_kernel<<<2048, 256, 0, stream>>>(f_, gbf);
  norms_kernel<<<512, 256, 0, stream>>>(f, fn2);
  norms_kernel<<<512, 256, 0, stream>>>(f_, gn2);
  hipMemsetAsync(rowmin, 0xFF, (size_t)TOTAL_ROWS * 4, stream);
  hipMemsetAsync(colmin, 0xFF, (size_t)TOTAL_ROWS * 4, stream);
  chamfer_mfma_kernel<<<512, 256, 0, stream>>>(f, gbf, fn2, gn2, rowmin, colmin);
  reduce_kernel<<<1, 256, 0, stream>>>(rowmin, colmin, (float*)d_out);
}